// Round 1
// baseline (1051.743 us; speedup 1.0000x reference)
//
#include <hip/hip_runtime.h>

#define D 64

// Prologue: c2[k] = ||centroid_k||^2
__global__ void c2_kernel(const float* __restrict__ centroids,
                          float* __restrict__ c2, int K) {
    int k = blockIdx.x * blockDim.x + threadIdx.x;
    if (k >= K) return;
    const float4* cp = (const float4*)(centroids + (size_t)k * D);
    float s = 0.f;
#pragma unroll
    for (int i = 0; i < D / 4; ++i) {
        float4 v = cp[i];
        s += v.x * v.x;
        s += v.y * v.y;
        s += v.z * v.z;
        s += v.w * v.w;
    }
    c2[k] = s;
}

// Main: per-thread point, loop all K centroids with wave-uniform addresses.
// score = ||c||^2 - 2 a.c   (same argmin as full squared distance)
__global__ __launch_bounds__(256) void encode_kernel(
    const float* __restrict__ action, const float* __restrict__ centroids,
    const float* __restrict__ c2, float* __restrict__ out_bin,
    float* __restrict__ out_res, int N, int K) {
    int n = blockIdx.x * blockDim.x + threadIdx.x;
    if (n >= N) return;

    float4 a[D / 4];
    const float4* ap = (const float4*)(action + (size_t)n * D);
#pragma unroll
    for (int i = 0; i < D / 4; ++i) a[i] = ap[i];

    float best = __builtin_inff();
    int bidx = 0;

    for (int k = 0; k < K; k += 4) {
        const float4* cp = (const float4*)(centroids + (size_t)k * D);
        float d0 = 0.f, d1 = 0.f, d2 = 0.f, d3 = 0.f;
#pragma unroll
        for (int i = 0; i < D / 4; ++i) {
            float4 av = a[i];
            float4 v0 = cp[i];
            float4 v1 = cp[i + 16];
            float4 v2 = cp[i + 32];
            float4 v3 = cp[i + 48];
            d0 += av.x * v0.x; d0 += av.y * v0.y; d0 += av.z * v0.z; d0 += av.w * v0.w;
            d1 += av.x * v1.x; d1 += av.y * v1.y; d1 += av.z * v1.z; d1 += av.w * v1.w;
            d2 += av.x * v2.x; d2 += av.y * v2.y; d2 += av.z * v2.z; d2 += av.w * v2.w;
            d3 += av.x * v3.x; d3 += av.y * v3.y; d3 += av.z * v3.z; d3 += av.w * v3.w;
        }
        // ascending-k strict < keeps numpy argmin first-min tie-break
        float s0 = fmaf(-2.f, d0, c2[k + 0]); if (s0 < best) { best = s0; bidx = k + 0; }
        float s1 = fmaf(-2.f, d1, c2[k + 1]); if (s1 < best) { best = s1; bidx = k + 1; }
        float s2 = fmaf(-2.f, d2, c2[k + 2]); if (s2 < best) { best = s2; bidx = k + 2; }
        float s3 = fmaf(-2.f, d3, c2[k + 3]); if (s3 < best) { best = s3; bidx = k + 3; }
    }

    out_bin[n] = (float)bidx;

    const float4* cb = (const float4*)(centroids + (size_t)bidx * D);
    float4* rp = (float4*)(out_res + (size_t)n * D);
#pragma unroll
    for (int i = 0; i < D / 4; ++i) {
        float4 cv = cb[i];
        float4 av = a[i];
        rp[i] = make_float4(av.x - cv.x, av.y - cv.y, av.z - cv.z, av.w - cv.w);
    }
}

extern "C" void kernel_launch(void* const* d_in, const int* in_sizes, int n_in,
                              void* d_out, int out_size, void* d_ws, size_t ws_size,
                              hipStream_t stream) {
    const float* action    = (const float*)d_in[0];   // [N, 64]
    const float* centroids = (const float*)d_in[1];   // [K, 64]
    int N = in_sizes[0] / D;   // 65536
    int K = in_sizes[1] / D;   // 2048

    float* out_bin = (float*)d_out;            // first N floats: argmin index
    float* out_res = (float*)d_out + N;        // then N*D residuals
    float* c2      = (float*)d_ws;             // K floats scratch

    c2_kernel<<<(K + 255) / 256, 256, 0, stream>>>(centroids, c2, K);
    encode_kernel<<<(N + 255) / 256, 256, 0, stream>>>(action, centroids, c2,
                                                       out_bin, out_res, N, K);
}

// Round 2
// 408.009 us; speedup vs baseline: 2.5777x; 2.5777x over previous
//
#include <hip/hip_runtime.h>

#define D 64
#define KSPLIT 4

// Prologue: c2[k] = ||centroid_k||^2
__global__ void c2_kernel(const float* __restrict__ centroids,
                          float* __restrict__ c2, int K) {
    int k = blockIdx.x * blockDim.x + threadIdx.x;
    if (k >= K) return;
    const float4* cp = (const float4*)(centroids + (size_t)k * D);
    float s = 0.f;
#pragma unroll
    for (int i = 0; i < D / 4; ++i) {
        float4 v = cp[i];
        s += v.x * v.x;
        s += v.y * v.y;
        s += v.z * v.z;
        s += v.w * v.w;
    }
    c2[k] = s;
}

// Main: per-thread point, K split across blockIdx.y for occupancy.
// score = ||c||^2 - 2 a.c   (same argmin as full squared distance)
__global__ __launch_bounds__(256, 1) void score_kernel(
    const float* __restrict__ action, const float* __restrict__ centroids,
    const float* __restrict__ c2, float2* __restrict__ cand, int N, int K) {
    int n = blockIdx.x * blockDim.x + threadIdx.x;
    if (n >= N) return;
    const int KC = K / KSPLIT;
    const int k0 = blockIdx.y * KC;
    const int k1 = k0 + KC;

    float4 a[D / 4];
    const float4* ap = (const float4*)(action + (size_t)n * D);
#pragma unroll
    for (int i = 0; i < D / 4; ++i) a[i] = ap[i];

    float best = __builtin_inff();
    int bidx = k0;

    for (int k = k0; k < k1; k += 4) {
        const float4* cp = (const float4*)(centroids + (size_t)k * D);
        float d0 = 0.f, d1 = 0.f, d2 = 0.f, d3 = 0.f;
#pragma unroll
        for (int i = 0; i < D / 4; ++i) {
            float4 av = a[i];
            float4 v0 = cp[i];
            float4 v1 = cp[i + 16];
            float4 v2 = cp[i + 32];
            float4 v3 = cp[i + 48];
            d0 += av.x * v0.x; d0 += av.y * v0.y; d0 += av.z * v0.z; d0 += av.w * v0.w;
            d1 += av.x * v1.x; d1 += av.y * v1.y; d1 += av.z * v1.z; d1 += av.w * v1.w;
            d2 += av.x * v2.x; d2 += av.y * v2.y; d2 += av.z * v2.z; d2 += av.w * v2.w;
            d3 += av.x * v3.x; d3 += av.y * v3.y; d3 += av.z * v3.z; d3 += av.w * v3.w;
        }
        // ascending-k strict < keeps numpy argmin first-min tie-break
        float s0 = fmaf(-2.f, d0, c2[k + 0]); if (s0 < best) { best = s0; bidx = k + 0; }
        float s1 = fmaf(-2.f, d1, c2[k + 1]); if (s1 < best) { best = s1; bidx = k + 1; }
        float s2 = fmaf(-2.f, d2, c2[k + 2]); if (s2 < best) { best = s2; bidx = k + 2; }
        float s3 = fmaf(-2.f, d3, c2[k + 3]); if (s3 < best) { best = s3; bidx = k + 3; }
    }

    cand[(size_t)blockIdx.y * N + n] = make_float2(best, (float)bidx);
}

// Reduce KSPLIT candidates per point, gather centroid, write bin + residual.
__global__ void finalize_kernel(const float* __restrict__ action,
                                const float* __restrict__ centroids,
                                const float2* __restrict__ cand,
                                float* __restrict__ out_bin,
                                float* __restrict__ out_res, int N) {
    int n = blockIdx.x * blockDim.x + threadIdx.x;
    if (n >= N) return;

    float best = __builtin_inff();
    int bidx = 0;
#pragma unroll
    for (int c = 0; c < KSPLIT; ++c) {
        // ascending chunk order + strict < preserves global first-min tie-break
        float2 v = cand[(size_t)c * N + n];
        if (v.x < best) { best = v.x; bidx = (int)v.y; }
    }

    out_bin[n] = (float)bidx;

    const float4* ap = (const float4*)(action + (size_t)n * D);
    const float4* cb = (const float4*)(centroids + (size_t)bidx * D);
    float4* rp = (float4*)(out_res + (size_t)n * D);
#pragma unroll
    for (int i = 0; i < D / 4; ++i) {
        float4 av = ap[i];
        float4 cv = cb[i];
        rp[i] = make_float4(av.x - cv.x, av.y - cv.y, av.z - cv.z, av.w - cv.w);
    }
}

extern "C" void kernel_launch(void* const* d_in, const int* in_sizes, int n_in,
                              void* d_out, int out_size, void* d_ws, size_t ws_size,
                              hipStream_t stream) {
    const float* action    = (const float*)d_in[0];   // [N, 64]
    const float* centroids = (const float*)d_in[1];   // [K, 64]
    int N = in_sizes[0] / D;   // 65536
    int K = in_sizes[1] / D;   // 2048

    float* out_bin = (float*)d_out;            // first N floats: argmin index
    float* out_res = (float*)d_out + N;        // then N*D residuals

    float*  c2   = (float*)d_ws;                       // K floats
    float2* cand = (float2*)((char*)d_ws + ((size_t)K * sizeof(float) + 255 & ~(size_t)255));
    // cand: KSPLIT * N float2 = 2 MB

    c2_kernel<<<(K + 255) / 256, 256, 0, stream>>>(centroids, c2, K);

    dim3 grid((N + 255) / 256, KSPLIT);
    score_kernel<<<grid, 256, 0, stream>>>(action, centroids, c2, cand, N, K);

    finalize_kernel<<<(N + 255) / 256, 256, 0, stream>>>(action, centroids, cand,
                                                         out_bin, out_res, N);
}

// Round 3
// 402.256 us; speedup vs baseline: 2.6146x; 1.0143x over previous
//
#include <hip/hip_runtime.h>

#define D 64
#define KSPLIT 4

// Prologue: c2[k] = ||centroid_k||^2
__global__ void c2_kernel(const float* __restrict__ centroids,
                          float* __restrict__ c2, int K) {
    int k = blockIdx.x * blockDim.x + threadIdx.x;
    if (k >= K) return;
    const float4* cp = (const float4*)(centroids + (size_t)k * D);
    float s = 0.f;
#pragma unroll
    for (int i = 0; i < D / 4; ++i) {
        float4 v = cp[i];
        s += v.x * v.x;
        s += v.y * v.y;
        s += v.z * v.z;
        s += v.w * v.w;
    }
    c2[k] = s;
}

// Main: per-thread point, K split across blockIdx.y for occupancy.
// score = ||c||^2 - 2 a.c   (same argmin as full squared distance)
__global__ __launch_bounds__(256, 1) void score_kernel(
    const float* __restrict__ action, const float* __restrict__ centroids,
    const float* __restrict__ c2, float2* __restrict__ cand, int N, int K) {
    int n = blockIdx.x * blockDim.x + threadIdx.x;
    if (n >= N) return;
    const int KC = K / KSPLIT;
    const int k0 = blockIdx.y * KC;
    const int k1 = k0 + KC;

    float4 a[D / 4];
    const float4* ap = (const float4*)(action + (size_t)n * D);
#pragma unroll
    for (int i = 0; i < D / 4; ++i) a[i] = ap[i];

    // Pin a[] in VGPRs: make each component opaque so the compiler cannot
    // rematerialize the global loads inside the k-loop (round-2 showed it
    // re-reads 256 B/thread/k4 from L1/L2 = ~8.6 TB total otherwise).
#pragma unroll
    for (int i = 0; i < D / 4; ++i) {
        asm volatile("" : "+v"(a[i].x), "+v"(a[i].y), "+v"(a[i].z), "+v"(a[i].w));
    }

    float best = __builtin_inff();
    int bidx = k0;

    for (int k = k0; k < k1; k += 4) {
        const float4* cp = (const float4*)(centroids + (size_t)k * D);
        float d0 = 0.f, d1 = 0.f, d2 = 0.f, d3 = 0.f;
#pragma unroll
        for (int i = 0; i < D / 4; ++i) {
            float4 av = a[i];
            float4 v0 = cp[i];
            float4 v1 = cp[i + 16];
            float4 v2 = cp[i + 32];
            float4 v3 = cp[i + 48];
            d0 = fmaf(av.x, v0.x, d0); d0 = fmaf(av.y, v0.y, d0);
            d0 = fmaf(av.z, v0.z, d0); d0 = fmaf(av.w, v0.w, d0);
            d1 = fmaf(av.x, v1.x, d1); d1 = fmaf(av.y, v1.y, d1);
            d1 = fmaf(av.z, v1.z, d1); d1 = fmaf(av.w, v1.w, d1);
            d2 = fmaf(av.x, v2.x, d2); d2 = fmaf(av.y, v2.y, d2);
            d2 = fmaf(av.z, v2.z, d2); d2 = fmaf(av.w, v2.w, d2);
            d3 = fmaf(av.x, v3.x, d3); d3 = fmaf(av.y, v3.y, d3);
            d3 = fmaf(av.z, v3.z, d3); d3 = fmaf(av.w, v3.w, d3);
        }
        // ascending-k strict < keeps numpy argmin first-min tie-break
        float s0 = fmaf(-2.f, d0, c2[k + 0]); if (s0 < best) { best = s0; bidx = k + 0; }
        float s1 = fmaf(-2.f, d1, c2[k + 1]); if (s1 < best) { best = s1; bidx = k + 1; }
        float s2 = fmaf(-2.f, d2, c2[k + 2]); if (s2 < best) { best = s2; bidx = k + 2; }
        float s3 = fmaf(-2.f, d3, c2[k + 3]); if (s3 < best) { best = s3; bidx = k + 3; }
    }

    cand[(size_t)blockIdx.y * N + n] = make_float2(best, (float)bidx);
}

// Reduce KSPLIT candidates per point, gather centroid, write bin + residual.
__global__ void finalize_kernel(const float* __restrict__ action,
                                const float* __restrict__ centroids,
                                const float2* __restrict__ cand,
                                float* __restrict__ out_bin,
                                float* __restrict__ out_res, int N) {
    int n = blockIdx.x * blockDim.x + threadIdx.x;
    if (n >= N) return;

    float best = __builtin_inff();
    int bidx = 0;
#pragma unroll
    for (int c = 0; c < KSPLIT; ++c) {
        // ascending chunk order + strict < preserves global first-min tie-break
        float2 v = cand[(size_t)c * N + n];
        if (v.x < best) { best = v.x; bidx = (int)v.y; }
    }

    out_bin[n] = (float)bidx;

    const float4* ap = (const float4*)(action + (size_t)n * D);
    const float4* cb = (const float4*)(centroids + (size_t)bidx * D);
    float4* rp = (float4*)(out_res + (size_t)n * D);
#pragma unroll
    for (int i = 0; i < D / 4; ++i) {
        float4 av = ap[i];
        float4 cv = cb[i];
        rp[i] = make_float4(av.x - cv.x, av.y - cv.y, av.z - cv.z, av.w - cv.w);
    }
}

extern "C" void kernel_launch(void* const* d_in, const int* in_sizes, int n_in,
                              void* d_out, int out_size, void* d_ws, size_t ws_size,
                              hipStream_t stream) {
    const float* action    = (const float*)d_in[0];   // [N, 64]
    const float* centroids = (const float*)d_in[1];   // [K, 64]
    int N = in_sizes[0] / D;   // 65536
    int K = in_sizes[1] / D;   // 2048

    float* out_bin = (float*)d_out;            // first N floats: argmin index
    float* out_res = (float*)d_out + N;        // then N*D residuals

    float*  c2   = (float*)d_ws;                       // K floats
    float2* cand = (float2*)((char*)d_ws + (((size_t)K * sizeof(float) + 255) & ~(size_t)255));
    // cand: KSPLIT * N float2 = 2 MB

    c2_kernel<<<(K + 255) / 256, 256, 0, stream>>>(centroids, c2, K);

    dim3 grid((N + 255) / 256, KSPLIT);
    score_kernel<<<grid, 256, 0, stream>>>(action, centroids, c2, cand, N, K);

    finalize_kernel<<<(N + 255) / 256, 256, 0, stream>>>(action, centroids, cand,
                                                         out_bin, out_res, N);
}

// Round 4
// 288.243 us; speedup vs baseline: 3.6488x; 1.3955x over previous
//
#include <hip/hip_runtime.h>

#define D 64
#define MT 128   // points per block tile
#define KT 128   // centroids per LDS tile
#define TM 8     // points per thread
#define TK 8     // centroids per thread

// Prologue: c2[k] = ||centroid_k||^2
__global__ void c2_kernel(const float* __restrict__ centroids,
                          float* __restrict__ c2, int K) {
    int k = blockIdx.x * blockDim.x + threadIdx.x;
    if (k >= K) return;
    const float4* cp = (const float4*)(centroids + (size_t)k * D);
    float s = 0.f;
#pragma unroll
    for (int i = 0; i < D / 4; ++i) {
        float4 v = cp[i];
        s += v.x * v.x;
        s += v.y * v.y;
        s += v.z * v.z;
        s += v.w * v.w;
    }
    c2[k] = s;
}

// Register-tiled distance GEMM + fused argmin + residual.
// score(n,k) = ||c_k||^2 - 2 a_n.c_k  (same argmin as squared distance)
__global__ __launch_bounds__(256, 2) void score_kernel(
    const float* __restrict__ action, const float* __restrict__ centroids,
    const float* __restrict__ c2g, float* __restrict__ out_bin,
    float* __restrict__ out_res, int N, int K) {

    // As: [d][m] 32 KB, Bs: [d][k] 32 KB (reused as reduction buf at end)
    __shared__ __align__(16) float smem[2 * D * MT];
    float* As = smem;
    float* Bs = smem + D * MT;

    const int tid = threadIdx.x;
    const int tx  = tid & 15;   // centroid group (cols tx*8 .. tx*8+7)
    const int ty  = tid >> 4;   // point group    (rows ty*8 .. ty*8+7)
    const int m0  = blockIdx.x * MT;

    // ---- stage A tile transposed: action[m0+r][dq..dq+3] -> As[d][r^g]
    // col-swizzle r^(dq&24) cuts staging write conflicts 16-way -> 4-way
    // while keeping frag reads b128-contiguous (swizzle bits >= 8).
    {
        const float4* asrc = (const float4*)(action + (size_t)m0 * D);
        const int dq = tx * 4;
        const int g  = dq & 24;
#pragma unroll
        for (int it = 0; it < 8; ++it) {
            const int r = ty + it * 16;
            float4 v = asrc[r * (D / 4) + tx];
            const int c = r ^ g;
            As[(dq + 0) * MT + c] = v.x;
            As[(dq + 1) * MT + c] = v.y;
            As[(dq + 2) * MT + c] = v.z;
            As[(dq + 3) * MT + c] = v.w;
        }
    }

    float bestv[TM];
    int   bestk[TM];
#pragma unroll
    for (int i = 0; i < TM; ++i) { bestv[i] = __builtin_inff(); bestk[i] = 0; }

    // register prefetch of B tile 0
    float4 breg[8];
    {
        const float4* bsrc = (const float4*)centroids;
#pragma unroll
        for (int it = 0; it < 8; ++it)
            breg[it] = bsrc[(ty + it * 16) * (D / 4) + tx];
    }

    const int KCHUNKS = K / KT;   // 16
    for (int kt = 0; kt < KCHUNKS; ++kt) {
        __syncthreads();          // previous tile's Bs reads complete
        // store prefetched B tile (transposed + swizzled)
        {
            const int dq = tx * 4;
            const int g  = dq & 24;
#pragma unroll
            for (int it = 0; it < 8; ++it) {
                const int r = ty + it * 16;
                const int c = r ^ g;
                float4 v = breg[it];
                Bs[(dq + 0) * KT + c] = v.x;
                Bs[(dq + 1) * KT + c] = v.y;
                Bs[(dq + 2) * KT + c] = v.z;
                Bs[(dq + 3) * KT + c] = v.w;
            }
        }
        // prefetch next tile into registers (latency hidden under d-loop)
        if (kt + 1 < KCHUNKS) {
            const float4* bsrc =
                (const float4*)(centroids + (size_t)(kt + 1) * KT * D);
#pragma unroll
            for (int it = 0; it < 8; ++it)
                breg[it] = bsrc[(ty + it * 16) * (D / 4) + tx];
        }
        __syncthreads();

        float acc[TM * TK];
#pragma unroll
        for (int i = 0; i < TM * TK; ++i) acc[i] = 0.f;

#pragma unroll 8
        for (int d = 0; d < D; ++d) {
            const int sc = d & 24;
            const float* Ar = &As[d * MT + ((8 * ty) ^ sc)];
            const float* Br = &Bs[d * KT + ((8 * tx) ^ sc)];
            float4 a0 = *(const float4*)(Ar);
            float4 a1 = *(const float4*)(Ar + 4);
            float4 b0 = *(const float4*)(Br);
            float4 b1 = *(const float4*)(Br + 4);
            float av[8] = {a0.x, a0.y, a0.z, a0.w, a1.x, a1.y, a1.z, a1.w};
            float bv[8] = {b0.x, b0.y, b0.z, b0.w, b1.x, b1.y, b1.z, b1.w};
#pragma unroll
            for (int i = 0; i < TM; ++i)
#pragma unroll
                for (int j = 0; j < TK; ++j)
                    acc[i * TK + j] = fmaf(av[i], bv[j], acc[i * TK + j]);
        }

        // fold tile scores into running argmin
        // ascending j + ascending kt + strict < = numpy first-min (per thread)
#pragma unroll
        for (int j = 0; j < TK; ++j) {
            const int k  = kt * KT + tx * TK + j;
            const float cc = c2g[k];
#pragma unroll
            for (int i = 0; i < TM; ++i) {
                const float s = fmaf(-2.f, acc[i * TK + j], cc);
                if (s < bestv[i]) { bestv[i] = s; bestk[i] = k; }
            }
        }
    }

    // ---- cross-thread argmin reduce (16 tx-slots per point) via LDS
    __syncthreads();
    float2* red = (float2*)Bs;   // 16 KB, overlays Bs
#pragma unroll
    for (int i = 0; i < TM; ++i)
        red[tx * MT + (ty * TM + i)] = make_float2(bestv[i], (float)bestk[i]);
    __syncthreads();

    // exact numpy tie-break: min score, then min index on equal score
    const int p    = tid & 127;
    const int half = tid >> 7;
    float best = __builtin_inff();
    int   bk   = 0x7fffffff;
#pragma unroll
    for (int t = 0; t < 16; ++t) {
        float2 v = red[t * MT + p];
        int vk = (int)v.y;
        if (v.x < best || (v.x == best && vk < bk)) { best = v.x; bk = vk; }
    }

    const int n = m0 + p;
    if (half == 0) out_bin[n] = (float)bk;

    const float4* cg = (const float4*)(centroids + (size_t)bk * D) + half * 8;
    float4*       rp = (float4*)(out_res + (size_t)n * D) + half * 8;
#pragma unroll
    for (int i = 0; i < 8; ++i) {
        const int d = half * 32 + i * 4;
        const int g = d & 24;      // (d..d+3)&24 identical (d % 4 == 0)
        float ax = As[(d + 0) * MT + (p ^ g)];
        float ay = As[(d + 1) * MT + (p ^ g)];
        float az = As[(d + 2) * MT + (p ^ g)];
        float aw = As[(d + 3) * MT + (p ^ g)];
        float4 c = cg[i];
        rp[i] = make_float4(ax - c.x, ay - c.y, az - c.z, aw - c.w);
    }
}

extern "C" void kernel_launch(void* const* d_in, const int* in_sizes, int n_in,
                              void* d_out, int out_size, void* d_ws, size_t ws_size,
                              hipStream_t stream) {
    const float* action    = (const float*)d_in[0];   // [N, 64]
    const float* centroids = (const float*)d_in[1];   // [K, 64]
    int N = in_sizes[0] / D;   // 65536
    int K = in_sizes[1] / D;   // 2048

    float* out_bin = (float*)d_out;       // first N floats: argmin index
    float* out_res = (float*)d_out + N;   // then N*D residuals
    float* c2      = (float*)d_ws;        // K floats scratch

    c2_kernel<<<(K + 255) / 256, 256, 0, stream>>>(centroids, c2, K);
    score_kernel<<<N / MT, 256, 0, stream>>>(action, centroids, c2,
                                             out_bin, out_res, N, K);
}